// Round 1
// baseline (187850.769 us; speedup 1.0000x reference)
//
#include <hip/hip_runtime.h>
#include <math.h>
#include <stdint.h>

#define T_SEQ 4096

// ---------------------------------------------------------------------------
// 2-level grid barrier (monotonic counters, agent scope).
// bar layout: group counter i at bar[i*32] (128 B apart), root at bar[512].
// ord is the 1-based barrier ordinal; target = 16*ord for both levels.
// ---------------------------------------------------------------------------
__device__ __forceinline__ void grid_barrier(uint32_t* bar, uint32_t ord) {
    __syncthreads();   // drains each wave's vmem (s_waitcnt vmcnt(0) before s_barrier)
    if (threadIdx.x == 0) {
        __threadfence();                       // agent release: wb L2
        const uint32_t target = 16u * ord;
        uint32_t* grp  = bar + ((blockIdx.x >> 4) << 5);
        uint32_t* root = bar + 512;
        __hip_atomic_fetch_add(grp, 1u, __ATOMIC_RELEASE, __HIP_MEMORY_SCOPE_AGENT);
        if ((blockIdx.x & 15) == 0) {
            while (__hip_atomic_load(grp, __ATOMIC_ACQUIRE, __HIP_MEMORY_SCOPE_AGENT) < target) { }
            __hip_atomic_fetch_add(root, 1u, __ATOMIC_RELEASE, __HIP_MEMORY_SCOPE_AGENT);
        }
        while (__hip_atomic_load(root, __ATOMIC_ACQUIRE, __HIP_MEMORY_SCOPE_AGENT) < target) { }
        __threadfence();                       // agent acquire: inv L1/L2
    }
    __syncthreads();
}

__device__ __forceinline__ float sigm(float x) { return 1.0f / (1.0f + expf(-x)); }

// ---------------------------------------------------------------------------
// fp32 NT GEMM with bias: C[m][j] = sum_k A[m][k]*B[j][k] + bias1[j]+bias2[j]
// M=8192 (rows 0..4095 from A0, 4096..8191 from A1), N=4096, K=1024.
// 128x128 tile, BK=16, 256 threads, 8x8 per thread.
// LDS columns stored with +4 floats of pad per 32 (2-way bank aliasing max).
// ---------------------------------------------------------------------------
__global__ void __launch_bounds__(256) gemm_nt_bias(
    const float* __restrict__ A0, const float* __restrict__ A1,
    const float* __restrict__ B,
    const float* __restrict__ bias1, const float* __restrict__ bias2,
    float* __restrict__ C)
{
    const int t  = threadIdx.x;
    const int tx = t & 15, ty = t >> 4;
    const int n0 = blockIdx.x * 128, m0 = blockIdx.y * 128;
    const float* Ab = (m0 < 4096) ? A0 : A1;
    const int ml0 = (m0 < 4096) ? m0 : (m0 - 4096);

    __shared__ float As[16 * 140];
    __shared__ float Bs[16 * 140];

    const int lr = t >> 1;               // 0..127: tile row loaded by this thread
    const int lh = t & 1;                // k half (0..7 / 8..15)
    const int pw = lr + ((lr >> 5) << 2);           // phys col for staging store
    const int pa = ty * 8 + ((ty >> 2) << 2);       // phys col for A frag read
    const int pb = tx * 8 + ((tx >> 2) << 2);       // phys col for B frag read

    float acc[8][8];
#pragma unroll
    for (int i = 0; i < 8; ++i)
#pragma unroll
        for (int j = 0; j < 8; ++j) acc[i][j] = 0.f;

    for (int k0 = 0; k0 < 1024; k0 += 16) {
        const float* ap = Ab + (size_t)(ml0 + lr) * 1024 + k0 + lh * 8;
        float4 av0 = *(const float4*)ap;
        float4 av1 = *(const float4*)(ap + 4);
        const float* bp = B + (size_t)(n0 + lr) * 1024 + k0 + lh * 8;
        float4 bv0 = *(const float4*)bp;
        float4 bv1 = *(const float4*)(bp + 4);

        __syncthreads();   // previous iteration's readers done
        const int kb = lh * 8;
        As[(kb + 0) * 140 + pw] = av0.x;  As[(kb + 1) * 140 + pw] = av0.y;
        As[(kb + 2) * 140 + pw] = av0.z;  As[(kb + 3) * 140 + pw] = av0.w;
        As[(kb + 4) * 140 + pw] = av1.x;  As[(kb + 5) * 140 + pw] = av1.y;
        As[(kb + 6) * 140 + pw] = av1.z;  As[(kb + 7) * 140 + pw] = av1.w;
        Bs[(kb + 0) * 140 + pw] = bv0.x;  Bs[(kb + 1) * 140 + pw] = bv0.y;
        Bs[(kb + 2) * 140 + pw] = bv0.z;  Bs[(kb + 3) * 140 + pw] = bv0.w;
        Bs[(kb + 4) * 140 + pw] = bv1.x;  Bs[(kb + 5) * 140 + pw] = bv1.y;
        Bs[(kb + 6) * 140 + pw] = bv1.z;  Bs[(kb + 7) * 140 + pw] = bv1.w;
        __syncthreads();

#pragma unroll
        for (int kk = 0; kk < 16; ++kk) {
            float4 a0 = *(const float4*)&As[kk * 140 + pa];
            float4 a1 = *(const float4*)&As[kk * 140 + pa + 4];
            float4 b0 = *(const float4*)&Bs[kk * 140 + pb];
            float4 b1 = *(const float4*)&Bs[kk * 140 + pb + 4];
            float a[8]  = {a0.x, a0.y, a0.z, a0.w, a1.x, a1.y, a1.z, a1.w};
            float bb[8] = {b0.x, b0.y, b0.z, b0.w, b1.x, b1.y, b1.z, b1.w};
#pragma unroll
            for (int i = 0; i < 8; ++i)
#pragma unroll
                for (int j = 0; j < 8; ++j)
                    acc[i][j] = fmaf(a[i], bb[j], acc[i][j]);
        }
    }

    const int j0 = n0 + tx * 8;
    float bsv[8];
#pragma unroll
    for (int j = 0; j < 8; ++j) bsv[j] = bias1[j0 + j] + bias2[j0 + j];
#pragma unroll
    for (int i = 0; i < 8; ++i) {
        size_t off = (size_t)(m0 + ty * 8 + i) * 4096 + j0;
        float4 v0, v1;
        v0.x = acc[i][0] + bsv[0]; v0.y = acc[i][1] + bsv[1];
        v0.z = acc[i][2] + bsv[2]; v0.w = acc[i][3] + bsv[3];
        v1.x = acc[i][4] + bsv[4]; v1.y = acc[i][5] + bsv[5];
        v1.z = acc[i][6] + bsv[6]; v1.w = acc[i][7] + bsv[7];
        *(float4*)(C + off)     = v0;
        *(float4*)(C + off + 4) = v1;
    }
}

// ---------------------------------------------------------------------------
// Persistent LSTM recurrence for one layer, both branches concurrently.
// 256 blocks x 256 threads (cooperative). Block b owns hidden units 4b..4b+3,
// i.e. gate rows {g*1024 + 4b + u}. W_hh rows live in VGPRs (64 regs/lane).
// Lane layout: row = tid&15 (gate*4+uoff), slice = tid>>4 (k in [64*slice,+64)).
// h broadcast: global hbuf (double buffered) -> LDS; slice-rotated float4
// reads are bank-conflict-free. G holds precomputed Wi@x + b_ih + b_hh.
// ---------------------------------------------------------------------------
__global__ void __launch_bounds__(256) lstm_rec(
    const float* __restrict__ Wh,   // [4096][1024] this layer's W_hh
    const float* __restrict__ G,    // [2][T][4096] input-gate preactivations
    const float* __restrict__ h0a, const float* __restrict__ h0b,  // [1024] each
    const float* __restrict__ c0a, const float* __restrict__ c0b,
    float* __restrict__ hbuf,       // [2 buf][2 br][1024]
    float* __restrict__ Hseq,       // [2][T][1024] h outputs (or null)
    float* __restrict__ o_out,      // [2][1024] final h (or null)
    uint32_t* __restrict__ bar)
{
    const int b = blockIdx.x, t = threadIdx.x;
    const int row = t & 15, slice = t >> 4;
    const int gate = row >> 2, uoff = row & 3;
    const int j_glob = gate * 1024 + b * 4 + uoff;

    // weights -> VGPRs, rotated to match the LDS broadcast traversal
    float4 w[16];
    {
        const float* wrow = Wh + (size_t)j_glob * 1024 + slice * 64;
#pragma unroll
        for (int m = 0; m < 16; ++m)
            w[m] = *(const float4*)(wrow + (((m + slice) & 15) << 2));
    }

    __shared__ float hs[2048];        // [br][1024]
    __shared__ float red[4][2][16];   // [wave][br][row]
    __shared__ float gl[2][16];       // gates per branch
    __shared__ float cst[2][4];       // cell state for owned units

    if (t < 8) {
        int br = t >> 2, u = t & 3;
        cst[br][u] = (br ? c0b : c0a)[b * 4 + u];
        hbuf[br * 1024 + b * 4 + u] = (br ? h0b : h0a)[b * 4 + u];  // buf 0
    }
    grid_barrier(bar, 1);   // initial h visible everywhere

    for (int step = 0; step < T_SEQ; ++step) {
        // stage h_t (8 KB) global -> LDS, coalesced
        {
            const float4* src = (const float4*)(hbuf + (step & 1) * 2048);
            float4* dst = (float4*)hs;
            dst[t]       = src[t];
            dst[t + 256] = src[t + 256];
        }
        // prefetch this block's G entries (latency hidden behind matvec)
        float gpre = 0.f;
        if (t < 32) {
            int br = t >> 4, rr = t & 15;
            int jj = (rr >> 2) * 1024 + b * 4 + (rr & 3);
            gpre = G[((size_t)br * T_SEQ + step) * 4096 + jj];
        }
        __syncthreads();

        float acc0 = 0.f, acc1 = 0.f;
        const float4* h4a = (const float4*)hs;
        const float4* h4b = (const float4*)(hs + 1024);
#pragma unroll
        for (int m = 0; m < 16; ++m) {
            int ci = (slice << 4) + ((m + slice) & 15);
            float4 ha = h4a[ci];
            float4 hb = h4b[ci];
            acc0 = fmaf(w[m].x, ha.x, acc0); acc0 = fmaf(w[m].y, ha.y, acc0);
            acc0 = fmaf(w[m].z, ha.z, acc0); acc0 = fmaf(w[m].w, ha.w, acc0);
            acc1 = fmaf(w[m].x, hb.x, acc1); acc1 = fmaf(w[m].y, hb.y, acc1);
            acc1 = fmaf(w[m].z, hb.z, acc1); acc1 = fmaf(w[m].w, hb.w, acc1);
        }
        // reduce the 4 slices resident in this wave (lane ^16, ^32 share row)
        acc0 += __shfl_xor(acc0, 16); acc0 += __shfl_xor(acc0, 32);
        acc1 += __shfl_xor(acc1, 16); acc1 += __shfl_xor(acc1, 32);
        const int wv = t >> 6, lane = t & 63;
        if (lane < 16) { red[wv][0][lane] = acc0; red[wv][1][lane] = acc1; }
        __syncthreads();
        if (t < 32) {
            int br = t >> 4, rr = t & 15;
            gl[br][rr] = red[0][br][rr] + red[1][br][rr] +
                         red[2][br][rr] + red[3][br][rr] + gpre;
        }
        __syncthreads();
        if (t < 8) {
            int br = t >> 2, u = t & 3;
            float gi = gl[br][u], gf = gl[br][4 + u], gg = gl[br][8 + u], go = gl[br][12 + u];
            float c = sigm(gf) * cst[br][u] + sigm(gi) * tanhf(gg);
            float h = sigm(go) * tanhf(c);
            cst[br][u] = c;
            hbuf[((step + 1) & 1) * 2048 + br * 1024 + b * 4 + u] = h;
            if (Hseq)  Hseq[((size_t)br * T_SEQ + step) * 1024 + b * 4 + u] = h;
            if (o_out != nullptr && step == T_SEQ - 1) o_out[br * 1024 + b * 4 + u] = h;
        }
        grid_barrier(bar, (uint32_t)step + 2);
    }
}

// ---------------------------------------------------------------------------
// out = 5*exp(-sum |o1 - o2|)
// ---------------------------------------------------------------------------
__global__ void __launch_bounds__(256) dist_kernel(const float* __restrict__ o,
                                                   float* __restrict__ out)
{
    int t = threadIdx.x;
    float s = 0.f;
    for (int i = t; i < 1024; i += 256) s += fabsf(o[i] - o[i + 1024]);
#pragma unroll
    for (int off = 1; off < 64; off <<= 1) s += __shfl_xor(s, off);
    __shared__ float r[4];
    if ((t & 63) == 0) r[t >> 6] = s;
    __syncthreads();
    if (t == 0) out[0] = 5.0f * expf(-(r[0] + r[1] + r[2] + r[3]));
}

// ---------------------------------------------------------------------------
extern "C" void kernel_launch(void* const* d_in, const int* in_sizes, int n_in,
                              void* d_out, int out_size, void* d_ws, size_t ws_size,
                              hipStream_t stream) {
    const float* s1   = (const float*)d_in[0];
    const float* s2   = (const float*)d_in[1];
    const float* h1_0 = (const float*)d_in[2];
    const float* c1_0 = (const float*)d_in[3];
    const float* h2_0 = (const float*)d_in[4];
    const float* c2_0 = (const float*)d_in[5];
    const float* W_ih = (const float*)d_in[6];
    const float* W_hh = (const float*)d_in[7];
    const float* b_ih = (const float*)d_in[8];
    const float* b_hh = (const float*)d_in[9];

    uint8_t* w8 = (uint8_t*)d_ws;
    uint32_t* bar0 = (uint32_t*)(w8);            // 4 KB
    uint32_t* bar1 = (uint32_t*)(w8 + 4096);     // 4 KB
    float* hbuf  = (float*)(w8 + 8192);          // 16 KB: [2][2][1024]
    float* o_out = (float*)(w8 + 24576);         // 8 KB:  [2][1024]
    float* G     = (float*)(w8 + 65536);         // 128 MB: [2][T][4096]
    float* Hseq  = (float*)(w8 + 65536 + 134217728ull);  // 32 MB: [2][T][1024]

    hipMemsetAsync(d_ws, 0, 8192, stream);       // zero both barrier regions

    dim3 ggrid(32, 64);
    // Phase 1: layer-0 input GEMM for both branches
    gemm_nt_bias<<<ggrid, 256, 0, stream>>>(s1, s2, W_ih, b_ih, b_hh, G);

    // Phase 2: layer-0 recurrence (both branches), store full h sequence
    {
        const float* Wh  = W_hh;
        const float* Gc  = G;
        const float* a0 = h1_0,  *a1 = h2_0, *cc0 = c1_0, *cc1 = c2_0;
        float* Hs = Hseq; float* oo = nullptr; float* hb = hbuf; uint32_t* br = bar0;
        void* args[] = { &Wh, &Gc, &a0, &a1, &cc0, &cc1, &hb, &Hs, &oo, &br };
        hipLaunchCooperativeKernel(lstm_rec, dim3(256), dim3(256), args, 0, stream);
    }

    // Phase 3: layer-1 input GEMM from h0 sequence
    gemm_nt_bias<<<ggrid, 256, 0, stream>>>(Hseq, Hseq + 4194304ull,
                                            W_ih + 4194304ull,
                                            b_ih + 4096, b_hh + 4096, G);

    // Phase 4: layer-1 recurrence, emit final h per branch
    {
        const float* Wh  = W_hh + 4194304ull;
        const float* Gc  = G;
        const float* a0 = h1_0 + 1024, *a1 = h2_0 + 1024;
        const float* cc0 = c1_0 + 1024, *cc1 = c2_0 + 1024;
        float* Hs = nullptr; float* oo = o_out; float* hb = hbuf; uint32_t* br = bar1;
        void* args[] = { &Wh, &Gc, &a0, &a1, &cc0, &cc1, &hb, &Hs, &oo, &br };
        hipLaunchCooperativeKernel(lstm_rec, dim3(256), dim3(256), args, 0, stream);
    }

    // Phase 5: scalar output
    dist_kernel<<<1, 256, 0, stream>>>(o_out, (float*)d_out);
}

// Round 2
// 36983.990 us; speedup vs baseline: 5.0792x; 5.0792x over previous
//
#include <hip/hip_runtime.h>
#include <math.h>
#include <stdint.h>

#define T_SEQ 4096

// ---------------------------------------------------------------------------
// Fast 2-level grid barrier for 256 blocks (16 groups x 16).
// bar layout (uint32 words, 128B line spacing):
//   arrival counter for group g : bar[g*32]          (g = 0..15)
//   release word    for group g : bar[512 + g*32]
//   root arrival counter        : bar[1024]
// All counters monotonic; ord is the 1-based barrier ordinal.
// Polls are RELAXED with s_sleep backoff (no per-poll buffer_inv, no line
// flooding); exactly one ACQUIRE load at exit provides the inv fence.
// Arrival fetch_add is RELEASE (writes back this block's stores).
// ---------------------------------------------------------------------------
__device__ __forceinline__ void grid_barrier(uint32_t* bar, uint32_t ord) {
    __syncthreads();
    if (threadIdx.x == 0) {
        const uint32_t target = 16u * ord;
        const int g = blockIdx.x >> 4;
        uint32_t* grp  = bar + g * 32;
        uint32_t* rel  = bar + 512 + g * 32;
        uint32_t* root = bar + 1024;
        __hip_atomic_fetch_add(grp, 1u, __ATOMIC_RELEASE, __HIP_MEMORY_SCOPE_AGENT);
        if ((blockIdx.x & 15) == 0) {
            while (__hip_atomic_load(grp, __ATOMIC_RELAXED, __HIP_MEMORY_SCOPE_AGENT) < target)
                __builtin_amdgcn_s_sleep(1);
            __hip_atomic_fetch_add(root, 1u, __ATOMIC_RELEASE, __HIP_MEMORY_SCOPE_AGENT);
            while (__hip_atomic_load(root, __ATOMIC_RELAXED, __HIP_MEMORY_SCOPE_AGENT) < target)
                __builtin_amdgcn_s_sleep(1);
            __hip_atomic_store(rel, ord, __ATOMIC_RELEASE, __HIP_MEMORY_SCOPE_AGENT);
        } else {
            while (__hip_atomic_load(rel, __ATOMIC_RELAXED, __HIP_MEMORY_SCOPE_AGENT) < ord)
                __builtin_amdgcn_s_sleep(1);
        }
        (void)__hip_atomic_load(root, __ATOMIC_ACQUIRE, __HIP_MEMORY_SCOPE_AGENT);
    }
    __syncthreads();
}

__device__ __forceinline__ float sigm(float x) { return 1.0f / (1.0f + expf(-x)); }

// ---------------------------------------------------------------------------
// fp32 NT GEMM with bias: C[m][j] = sum_k A[m][k]*B[j][k] + bias1[j]+bias2[j]
// M=8192 (rows 0..4095 from A0, 4096..8191 from A1), N=4096, K=1024.
// (unchanged from R0 — passed; layer-0 input preactivations only)
// ---------------------------------------------------------------------------
__global__ void __launch_bounds__(256) gemm_nt_bias(
    const float* __restrict__ A0, const float* __restrict__ A1,
    const float* __restrict__ B,
    const float* __restrict__ bias1, const float* __restrict__ bias2,
    float* __restrict__ C)
{
    const int t  = threadIdx.x;
    const int tx = t & 15, ty = t >> 4;
    const int n0 = blockIdx.x * 128, m0 = blockIdx.y * 128;
    const float* Ab = (m0 < 4096) ? A0 : A1;
    const int ml0 = (m0 < 4096) ? m0 : (m0 - 4096);

    __shared__ float As[16 * 140];
    __shared__ float Bs[16 * 140];

    const int lr = t >> 1;
    const int lh = t & 1;
    const int pw = lr + ((lr >> 5) << 2);
    const int pa = ty * 8 + ((ty >> 2) << 2);
    const int pb = tx * 8 + ((tx >> 2) << 2);

    float acc[8][8];
#pragma unroll
    for (int i = 0; i < 8; ++i)
#pragma unroll
        for (int j = 0; j < 8; ++j) acc[i][j] = 0.f;

    for (int k0 = 0; k0 < 1024; k0 += 16) {
        const float* ap = Ab + (size_t)(ml0 + lr) * 1024 + k0 + lh * 8;
        float4 av0 = *(const float4*)ap;
        float4 av1 = *(const float4*)(ap + 4);
        const float* bp = B + (size_t)(n0 + lr) * 1024 + k0 + lh * 8;
        float4 bv0 = *(const float4*)bp;
        float4 bv1 = *(const float4*)(bp + 4);

        __syncthreads();
        const int kb = lh * 8;
        As[(kb + 0) * 140 + pw] = av0.x;  As[(kb + 1) * 140 + pw] = av0.y;
        As[(kb + 2) * 140 + pw] = av0.z;  As[(kb + 3) * 140 + pw] = av0.w;
        As[(kb + 4) * 140 + pw] = av1.x;  As[(kb + 5) * 140 + pw] = av1.y;
        As[(kb + 6) * 140 + pw] = av1.z;  As[(kb + 7) * 140 + pw] = av1.w;
        Bs[(kb + 0) * 140 + pw] = bv0.x;  Bs[(kb + 1) * 140 + pw] = bv0.y;
        Bs[(kb + 2) * 140 + pw] = bv0.z;  Bs[(kb + 3) * 140 + pw] = bv0.w;
        Bs[(kb + 4) * 140 + pw] = bv1.x;  Bs[(kb + 5) * 140 + pw] = bv1.y;
        Bs[(kb + 6) * 140 + pw] = bv1.z;  Bs[(kb + 7) * 140 + pw] = bv1.w;
        __syncthreads();

#pragma unroll
        for (int kk = 0; kk < 16; ++kk) {
            float4 a0 = *(const float4*)&As[kk * 140 + pa];
            float4 a1 = *(const float4*)&As[kk * 140 + pa + 4];
            float4 b0 = *(const float4*)&Bs[kk * 140 + pb];
            float4 b1 = *(const float4*)&Bs[kk * 140 + pb + 4];
            float a[8]  = {a0.x, a0.y, a0.z, a0.w, a1.x, a1.y, a1.z, a1.w};
            float bb[8] = {b0.x, b0.y, b0.z, b0.w, b1.x, b1.y, b1.z, b1.w};
#pragma unroll
            for (int i = 0; i < 8; ++i)
#pragma unroll
                for (int j = 0; j < 8; ++j)
                    acc[i][j] = fmaf(a[i], bb[j], acc[i][j]);
        }
    }

    const int j0 = n0 + tx * 8;
    float bsv[8];
#pragma unroll
    for (int j = 0; j < 8; ++j) bsv[j] = bias1[j0 + j] + bias2[j0 + j];
#pragma unroll
    for (int i = 0; i < 8; ++i) {
        size_t off = (size_t)(m0 + ty * 8 + i) * 4096 + j0;
        float4 v0, v1;
        v0.x = acc[i][0] + bsv[0]; v0.y = acc[i][1] + bsv[1];
        v0.z = acc[i][2] + bsv[2]; v0.w = acc[i][3] + bsv[3];
        v1.x = acc[i][4] + bsv[4]; v1.y = acc[i][5] + bsv[5];
        v1.z = acc[i][6] + bsv[6]; v1.w = acc[i][7] + bsv[7];
        *(float4*)(C + off)     = v0;
        *(float4*)(C + off + 4) = v1;
    }
}

// ---------------------------------------------------------------------------
// Fused layer-pipelined LSTM recurrence, both layers + both branches in one
// cooperative dispatch. 256 blocks x 256 threads, 1 block/CU.
// Tick tau (0..4096): layer 0 computes step tau (tau<=4095); layer 1 computes
// step tau-1 (tau>=1). Block b owns hidden units 4b..4b+3 of BOTH layers.
// Per-thread VGPR weights (192 regs): w0 = W_hh(l0) row, w1h = W_hh(l1) row,
// w1i = W_ih(l1) row. Lane layout: row = t&15 (gate*4+u), slice = t>>4.
// hbuf: [buf][layer][br][1024] double-buffered; writes at tick tau -> buf
// tau&1, reads at tick tau <- buf (tau+1)&1. One grid barrier per tick.
// G holds layer-0 preactivations (Wi@s + b_ih0 + b_hh0) from the GEMM.
// ---------------------------------------------------------------------------
__global__ void __launch_bounds__(256, 1) lstm_fused(
    const float* __restrict__ W_hh,  // [2][4096][1024]
    const float* __restrict__ W_ih,  // [2][4096][1024]
    const float* __restrict__ b_ih,  // [2][4096]
    const float* __restrict__ b_hh,  // [2][4096]
    const float* __restrict__ G,     // [2 br][T][4096] layer-0 preacts
    const float* __restrict__ h1_0, const float* __restrict__ c1_0,  // [2][1024]
    const float* __restrict__ h2_0, const float* __restrict__ c2_0,
    float* __restrict__ hbuf,        // [2 buf][2 layer][2 br][1024]
    float* __restrict__ o_out,       // [2 br][1024] final layer-1 h
    uint32_t* __restrict__ bar)
{
    const int b = blockIdx.x, t = threadIdx.x;
    const int row = t & 15, slice = t >> 4;
    const int gate = row >> 2, uoff = row & 3;
    const int j_glob = gate * 1024 + b * 4 + uoff;   // gate-row within a layer

    // ---- weights -> VGPRs (rotated to match LDS traversal) ----
    float4 w0[16], w1h[16], w1i[16];
    {
        const float* r0 = W_hh + (size_t)j_glob * 1024 + slice * 64;
        const float* r1 = W_hh + 4194304ull + (size_t)j_glob * 1024 + slice * 64;
        const float* r2 = W_ih + 4194304ull + (size_t)j_glob * 1024 + slice * 64;
#pragma unroll
        for (int m = 0; m < 16; ++m) {
            const int o = ((m + slice) & 15) << 2;
            w0[m]  = *(const float4*)(r0 + o);
            w1h[m] = *(const float4*)(r1 + o);
            w1i[m] = *(const float4*)(r2 + o);
        }
    }

    __shared__ float hs[4096];        // [4 vec][1024]: h0p_b0, h0p_b1, h1p_b0, h1p_b1
    __shared__ float red[4][4][16];   // [wave][acc][row]
    __shared__ float gl[4][16];       // [layer*2+br][row] assembled gates
    __shared__ float bl1s[16];        // layer-1 bias for owned rows

    // ---- per-thread cell state for t<16: layer=t>>3, br=(t>>2)&1, u=t&3 ----
    float creg = 0.f;
    if (t < 16) {
        const int layer = t >> 3, br = (t >> 2) & 1, u = t & 3;
        const float* cc = br ? c2_0 : c1_0;
        const float* hh = br ? h2_0 : h1_0;
        creg = cc[layer * 1024 + b * 4 + u];
        const float hinit = hh[layer * 1024 + b * 4 + u];
        hbuf[4096 + layer * 2048 + br * 1024 + b * 4 + u] = hinit;      // buf1
        if (layer == 1)
            hbuf[2048 + br * 1024 + b * 4 + u] = hinit;                 // buf0.h1
    }
    if (t >= 32 && t < 48) {          // layer-1 bias (same for both branches)
        const int rr = t & 15;
        const int jj = 4096 + (rr >> 2) * 1024 + b * 4 + (rr & 3);
        bl1s[rr] = b_ih[jj] + b_hh[jj];
    }
    grid_barrier(bar, 1);             // initial states visible grid-wide

    for (int tick = 0; tick <= T_SEQ; ++tick) {
        // ---- stage h_prev (16 KB) global -> LDS, coalesced ----
        {
            const float4* src = (const float4*)(hbuf + ((tick + 1) & 1) * 4096);
            float4* dst = (float4*)hs;
            dst[t]       = src[t];
            dst[t + 256] = src[t + 256];
            dst[t + 512] = src[t + 512];
            dst[t + 768] = src[t + 768];
        }
        // ---- prefetch layer-0 G entries (t<32: br=t>>4, row=t&15) ----
        float gpre = 0.f;
        if (t < 32) {
            const int br = t >> 4, rr = t & 15;
            const int jj = (rr >> 2) * 1024 + b * 4 + (rr & 3);
            const int st = (tick < T_SEQ) ? tick : (T_SEQ - 1);   // clamp; unused at 4096
            gpre = G[((size_t)br * T_SEQ + st) * 4096 + jj];
        }
        __syncthreads();

        // ---- 3 matvecs over owned rows ----
        float a00 = 0.f, a01 = 0.f, a10 = 0.f, a11 = 0.f;
        const float4* H00 = (const float4*)hs;
        const float4* H01 = (const float4*)(hs + 1024);
        const float4* H10 = (const float4*)(hs + 2048);
        const float4* H11 = (const float4*)(hs + 3072);
#pragma unroll
        for (int m = 0; m < 16; ++m) {
            const int ci = (slice << 4) + ((m + slice) & 15);
            const float4 x0 = H00[ci], x1 = H01[ci];
            const float4 y0 = H10[ci], y1 = H11[ci];
            a00 = fmaf(w0[m].x, x0.x, a00); a00 = fmaf(w0[m].y, x0.y, a00);
            a00 = fmaf(w0[m].z, x0.z, a00); a00 = fmaf(w0[m].w, x0.w, a00);
            a01 = fmaf(w0[m].x, x1.x, a01); a01 = fmaf(w0[m].y, x1.y, a01);
            a01 = fmaf(w0[m].z, x1.z, a01); a01 = fmaf(w0[m].w, x1.w, a01);
            a10 = fmaf(w1i[m].x, x0.x, a10); a10 = fmaf(w1i[m].y, x0.y, a10);
            a10 = fmaf(w1i[m].z, x0.z, a10); a10 = fmaf(w1i[m].w, x0.w, a10);
            a10 = fmaf(w1h[m].x, y0.x, a10); a10 = fmaf(w1h[m].y, y0.y, a10);
            a10 = fmaf(w1h[m].z, y0.z, a10); a10 = fmaf(w1h[m].w, y0.w, a10);
            a11 = fmaf(w1i[m].x, x1.x, a11); a11 = fmaf(w1i[m].y, x1.y, a11);
            a11 = fmaf(w1i[m].z, x1.z, a11); a11 = fmaf(w1i[m].w, x1.w, a11);
            a11 = fmaf(w1h[m].x, y1.x, a11); a11 = fmaf(w1h[m].y, y1.y, a11);
            a11 = fmaf(w1h[m].z, y1.z, a11); a11 = fmaf(w1h[m].w, y1.w, a11);
        }
        // ---- reduce 4 slices within wave (lanes ^16, ^32 share a row) ----
        a00 += __shfl_xor(a00, 16); a00 += __shfl_xor(a00, 32);
        a01 += __shfl_xor(a01, 16); a01 += __shfl_xor(a01, 32);
        a10 += __shfl_xor(a10, 16); a10 += __shfl_xor(a10, 32);
        a11 += __shfl_xor(a11, 16); a11 += __shfl_xor(a11, 32);
        const int wv = t >> 6, lane = t & 63;
        if (lane < 16) {
            red[wv][0][lane] = a00; red[wv][1][lane] = a01;
            red[wv][2][lane] = a10; red[wv][3][lane] = a11;
        }
        __syncthreads();
        // ---- assemble gates: t<64, lb=t>>4 in {L0b0,L0b1,L1b0,L1b1} ----
        if (t < 64) {
            const int lb = t >> 4, rr = t & 15;
            float s = red[0][lb][rr] + red[1][lb][rr] + red[2][lb][rr] + red[3][lb][rr];
            s += (lb < 2) ? gpre : bl1s[rr];
            gl[lb][rr] = s;
        }
        __syncthreads();
        // ---- cell update: t<16 (layer=t>>3, br=(t>>2)&1, u=t&3) ----
        if (t < 16) {
            const int layer = t >> 3, br = (t >> 2) & 1, u = t & 3;
            const bool active = (layer == 0) ? (tick < T_SEQ) : (tick >= 1);
            if (active) {
                const int lb = layer * 2 + br;
                const float gi = gl[lb][u],     gf = gl[lb][4 + u];
                const float gg = gl[lb][8 + u], go = gl[lb][12 + u];
                const float c = sigm(gf) * creg + sigm(gi) * tanhf(gg);
                const float h = sigm(go) * tanhf(c);
                creg = c;
                hbuf[(tick & 1) * 4096 + layer * 2048 + br * 1024 + b * 4 + u] = h;
                if (layer == 1 && tick == T_SEQ)
                    o_out[br * 1024 + b * 4 + u] = h;
            }
        }
        grid_barrier(bar, (uint32_t)tick + 2);
    }
}

// ---------------------------------------------------------------------------
// out = 5*exp(-sum |o1 - o2|)
// ---------------------------------------------------------------------------
__global__ void __launch_bounds__(256) dist_kernel(const float* __restrict__ o,
                                                   float* __restrict__ out)
{
    int t = threadIdx.x;
    float s = 0.f;
    for (int i = t; i < 1024; i += 256) s += fabsf(o[i] - o[i + 1024]);
#pragma unroll
    for (int off = 1; off < 64; off <<= 1) s += __shfl_xor(s, off);
    __shared__ float r[4];
    if ((t & 63) == 0) r[t >> 6] = s;
    __syncthreads();
    if (t == 0) out[0] = 5.0f * expf(-(r[0] + r[1] + r[2] + r[3]));
}

// ---------------------------------------------------------------------------
extern "C" void kernel_launch(void* const* d_in, const int* in_sizes, int n_in,
                              void* d_out, int out_size, void* d_ws, size_t ws_size,
                              hipStream_t stream) {
    const float* s1   = (const float*)d_in[0];
    const float* s2   = (const float*)d_in[1];
    const float* h1_0 = (const float*)d_in[2];
    const float* c1_0 = (const float*)d_in[3];
    const float* h2_0 = (const float*)d_in[4];
    const float* c2_0 = (const float*)d_in[5];
    const float* W_ih = (const float*)d_in[6];
    const float* W_hh = (const float*)d_in[7];
    const float* b_ih = (const float*)d_in[8];
    const float* b_hh = (const float*)d_in[9];

    uint8_t* w8 = (uint8_t*)d_ws;
    uint32_t* bar  = (uint32_t*)(w8);            // 8 KB barrier region
    float* hbuf  = (float*)(w8 + 8192);          // 32 KB: [2][2][2][1024]
    float* o_out = (float*)(w8 + 8192 + 32768);  // 8 KB:  [2][1024]
    float* G     = (float*)(w8 + 65536);         // 128 MB: [2][T][4096]

    hipMemsetAsync(d_ws, 0, 8192, stream);       // zero barrier counters

    // Phase 1: layer-0 input GEMM for both branches
    dim3 ggrid(32, 64);
    gemm_nt_bias<<<ggrid, 256, 0, stream>>>(s1, s2, W_ih, b_ih, b_hh, G);

    // Phase 2: fused layer-pipelined recurrence (single cooperative dispatch)
    {
        const float* whh = W_hh; const float* wih = W_ih;
        const float* bi = b_ih;  const float* bh = b_hh;
        const float* gg = G;
        const float* h1p = h1_0; const float* c1p = c1_0;
        const float* h2p = h2_0; const float* c2p = c2_0;
        float* hb = hbuf; float* oo = o_out; uint32_t* br = bar;
        void* args[] = { &whh, &wih, &bi, &bh, &gg,
                         &h1p, &c1p, &h2p, &c2p, &hb, &oo, &br };
        hipLaunchCooperativeKernel(lstm_fused, dim3(256), dim3(256), args, 0, stream);
    }

    // Phase 3: scalar output
    dist_kernel<<<1, 256, 0, stream>>>(o_out, (float*)d_out);
}

// Round 4
// 16726.222 us; speedup vs baseline: 11.2309x; 2.2111x over previous
//
#include <hip/hip_runtime.h>
#include <math.h>
#include <stdint.h>

#define T_SEQ 4096

__device__ __forceinline__ float sigm(float x) { return 1.0f / (1.0f + expf(-x)); }

// ---------------------------------------------------------------------------
// Fence-free grid barrier, called by WAVE 0 ONLY (t < 64).
// All cross-block data travels via relaxed agent-scope atomics (empirically
// LLC-coherent on gfx950 — proven by R1/R2 barrier progress), so no
// buffer_wbl2 / buffer_inv fences are needed anywhere.
// bar[g*32]       : arrival counter, group g (16 blocks/group), monotonic
// bar[512 + g*32] : release word, group g (stores latest completed ord)
// Block 0 lanes 0..15 poll the 16 counters in parallel, then broadcast.
// ---------------------------------------------------------------------------
__device__ __forceinline__ void wave0_barrier(uint32_t* bar, uint32_t ord, int t) {
    if (t == 0)
        __hip_atomic_fetch_add(bar + ((blockIdx.x >> 4) << 5), 1u,
                               __ATOMIC_RELAXED, __HIP_MEMORY_SCOPE_AGENT);
    if (blockIdx.x == 0) {
        if (t < 16) {
            uint32_t* cnt = bar + (t << 5);
            while (__hip_atomic_load(cnt, __ATOMIC_RELAXED, __HIP_MEMORY_SCOPE_AGENT) < (ord << 4))
                __builtin_amdgcn_s_sleep(1);
            // reconvergence: all 16 lanes' loops done -> all 256 blocks arrived
            __hip_atomic_store(bar + 512 + (t << 5), ord,
                               __ATOMIC_RELAXED, __HIP_MEMORY_SCOPE_AGENT);
        }
    } else if (t == 0) {
        uint32_t* rel = bar + 512 + ((blockIdx.x >> 4) << 5);
        while (__hip_atomic_load(rel, __ATOMIC_RELAXED, __HIP_MEMORY_SCOPE_AGENT) < ord)
            __builtin_amdgcn_s_sleep(1);
    }
}

// ---------------------------------------------------------------------------
// fp32 NT GEMM with bias: layer-0 preactivations for both branches.
// C[m][p(j)] = sum_k A[m][k]*B[j][k] + bias1[j]+bias2[j]
// Column permutation p(j): j = gate*1024 + 4b+u  ->  b*16 + gate*4 + u, so
// each recurrence block's 16 gate preacts are one contiguous 64 B line.
// ---------------------------------------------------------------------------
__global__ void __launch_bounds__(256) gemm_nt_bias(
    const float* __restrict__ A0, const float* __restrict__ A1,
    const float* __restrict__ B,
    const float* __restrict__ bias1, const float* __restrict__ bias2,
    float* __restrict__ C)
{
    const int t  = threadIdx.x;
    const int tx = t & 15, ty = t >> 4;
    const int n0 = blockIdx.x * 128, m0 = blockIdx.y * 128;
    const float* Ab = (m0 < 4096) ? A0 : A1;
    const int ml0 = (m0 < 4096) ? m0 : (m0 - 4096);

    __shared__ float As[16 * 140];
    __shared__ float Bs[16 * 140];

    const int lr = t >> 1;
    const int lh = t & 1;
    const int pw = lr + ((lr >> 5) << 2);
    const int pa = ty * 8 + ((ty >> 2) << 2);
    const int pb = tx * 8 + ((tx >> 2) << 2);

    float acc[8][8];
#pragma unroll
    for (int i = 0; i < 8; ++i)
#pragma unroll
        for (int j = 0; j < 8; ++j) acc[i][j] = 0.f;

    for (int k0 = 0; k0 < 1024; k0 += 16) {
        const float* ap = Ab + (size_t)(ml0 + lr) * 1024 + k0 + lh * 8;
        float4 av0 = *(const float4*)ap;
        float4 av1 = *(const float4*)(ap + 4);
        const float* bp = B + (size_t)(n0 + lr) * 1024 + k0 + lh * 8;
        float4 bv0 = *(const float4*)bp;
        float4 bv1 = *(const float4*)(bp + 4);

        __syncthreads();
        const int kb = lh * 8;
        As[(kb + 0) * 140 + pw] = av0.x;  As[(kb + 1) * 140 + pw] = av0.y;
        As[(kb + 2) * 140 + pw] = av0.z;  As[(kb + 3) * 140 + pw] = av0.w;
        As[(kb + 4) * 140 + pw] = av1.x;  As[(kb + 5) * 140 + pw] = av1.y;
        As[(kb + 6) * 140 + pw] = av1.z;  As[(kb + 7) * 140 + pw] = av1.w;
        Bs[(kb + 0) * 140 + pw] = bv0.x;  Bs[(kb + 1) * 140 + pw] = bv0.y;
        Bs[(kb + 2) * 140 + pw] = bv0.z;  Bs[(kb + 3) * 140 + pw] = bv0.w;
        Bs[(kb + 4) * 140 + pw] = bv1.x;  Bs[(kb + 5) * 140 + pw] = bv1.y;
        Bs[(kb + 6) * 140 + pw] = bv1.z;  Bs[(kb + 7) * 140 + pw] = bv1.w;
        __syncthreads();

#pragma unroll
        for (int kk = 0; kk < 16; ++kk) {
            float4 a0 = *(const float4*)&As[kk * 140 + pa];
            float4 a1 = *(const float4*)&As[kk * 140 + pa + 4];
            float4 b0 = *(const float4*)&Bs[kk * 140 + pb];
            float4 b1 = *(const float4*)&Bs[kk * 140 + pb + 4];
            float a[8]  = {a0.x, a0.y, a0.z, a0.w, a1.x, a1.y, a1.z, a1.w};
            float bb[8] = {b0.x, b0.y, b0.z, b0.w, b1.x, b1.y, b1.z, b1.w};
#pragma unroll
            for (int i = 0; i < 8; ++i)
#pragma unroll
                for (int j = 0; j < 8; ++j)
                    acc[i][j] = fmaf(a[i], bb[j], acc[i][j]);
        }
    }

    const int gcol  = n0 >> 10;              // gate for this whole block-column
    const int qbase = (n0 & 1023) + tx * 8;  // 4b+u base
    const int j0 = n0 + tx * 8;
    float bsv[8];
#pragma unroll
    for (int j = 0; j < 8; ++j) bsv[j] = bias1[j0 + j] + bias2[j0 + j];
#pragma unroll
    for (int i = 0; i < 8; ++i) {
        const size_t rowoff = (size_t)(m0 + ty * 8 + i) * 4096;
#pragma unroll
        for (int jj = 0; jj < 8; ++jj) {
            const int q = qbase + jj;
            C[rowoff + ((q >> 2) << 4) + (gcol << 2) + (q & 3)] = acc[i][jj] + bsv[jj];
        }
    }
}

// ---------------------------------------------------------------------------
// Fused layer-pipelined LSTM recurrence (one cooperative dispatch).
// 256 blocks x 256 threads. Tick tau: layer0 step tau, layer1 step tau-1.
// Cross-block h transport: relaxed agent atomic stores + relaxed agent atomic
// loads (both proven coherent on gfx950 by barrier behavior). No fences.
// ---------------------------------------------------------------------------
__global__ void __launch_bounds__(256, 1) lstm_fused(
    const float* __restrict__ W_hh,  // [2][4096][1024]
    const float* __restrict__ W_ih,  // [2][4096][1024]
    const float* __restrict__ b_ih,  // [2][4096]
    const float* __restrict__ b_hh,  // [2][4096]
    const float* __restrict__ G,     // [2 br][T][4096] permuted layer-0 preacts
    const float* __restrict__ h1_0, const float* __restrict__ c1_0,
    const float* __restrict__ h2_0, const float* __restrict__ c2_0,
    float* __restrict__ hbuf,        // [2 buf][2 layer][2 br][1024]
    float* __restrict__ o_out,       // [2 br][1024]
    uint32_t* __restrict__ bar)
{
    const int b = blockIdx.x, t = threadIdx.x;
    const int row = t & 15, slice = t >> 4;
    const int gate = row >> 2, uoff = row & 3;
    const int j_glob = gate * 1024 + b * 4 + uoff;

    // ---- weights -> registers (rotated to match LDS traversal) ----
    float4 w0[16], w1h[16], w1i[16];
    {
        const float* r0 = W_hh + (size_t)j_glob * 1024 + slice * 64;
        const float* r1 = W_hh + 4194304ull + (size_t)j_glob * 1024 + slice * 64;
        const float* r2 = W_ih + 4194304ull + (size_t)j_glob * 1024 + slice * 64;
#pragma unroll
        for (int m = 0; m < 16; ++m) {
            const int o = ((m + slice) & 15) << 2;
            w0[m]  = *(const float4*)(r0 + o);
            w1h[m] = *(const float4*)(r1 + o);
            w1i[m] = *(const float4*)(r2 + o);
        }
    }

    __shared__ float hs[4096];        // [4 vec][1024]
    __shared__ float red[4][4][16];   // [wave][acc][row]
    __shared__ float bl1s[16];        // layer-1 bias for owned rows

    float creg = 0.f;
    if (t < 16) {
        const int layer = t >> 3, br = (t >> 2) & 1, u = t & 3;
        const float* cc = br ? c2_0 : c1_0;
        const float* hh = br ? h2_0 : h1_0;
        creg = cc[layer * 1024 + b * 4 + u];
        const float hinit = hh[layer * 1024 + b * 4 + u];
        __hip_atomic_store(&hbuf[4096 + layer * 2048 + br * 1024 + b * 4 + u],
                           hinit, __ATOMIC_RELAXED, __HIP_MEMORY_SCOPE_AGENT);
        if (layer == 1)
            __hip_atomic_store(&hbuf[2048 + br * 1024 + b * 4 + u],
                               hinit, __ATOMIC_RELAXED, __HIP_MEMORY_SCOPE_AGENT);
    }
    if (t >= 32 && t < 48) {
        const int rr = t & 15;
        const int jj = 4096 + (rr >> 2) * 1024 + b * 4 + (rr & 3);
        bl1s[rr] = b_ih[jj] + b_hh[jj];
    }
    if (t < 64) {
        asm volatile("s_waitcnt vmcnt(0)" ::: "memory");
        wave0_barrier(bar, 1u, t);
    }
    __syncthreads();

    for (int tick = 0; tick <= T_SEQ; ++tick) {
        // ---- stage h_prev (16 KB) LLC -> LDS via relaxed agent atomic loads ----
        {
            const float* src = hbuf + ((tick + 1) & 1) * 4096;
            float v[16];
#pragma unroll
            for (int r = 0; r < 16; ++r)
                v[r] = __hip_atomic_load(src + t + r * 256, __ATOMIC_RELAXED,
                                         __HIP_MEMORY_SCOPE_AGENT);
#pragma unroll
            for (int r = 0; r < 16; ++r)
                hs[t + r * 256] = v[r];
        }
        // ---- layer-0 G prefetch: lane t<32 gets row rr of branch t>>4 ----
        float gpre = 0.f;
        if (t < 32) {
            const int br = t >> 4, rr = t & 15;
            const int st = (tick < T_SEQ) ? tick : (T_SEQ - 1);
            gpre = G[((size_t)br * T_SEQ + st) * 4096 + b * 16 + rr];
        }
        __syncthreads();

        // ---- 3 matvecs over owned rows ----
        float a00 = 0.f, a01 = 0.f, a10 = 0.f, a11 = 0.f;
        const float4* H00 = (const float4*)hs;
        const float4* H01 = (const float4*)(hs + 1024);
        const float4* H10 = (const float4*)(hs + 2048);
        const float4* H11 = (const float4*)(hs + 3072);
#pragma unroll
        for (int m = 0; m < 16; ++m) {
            const int ci = (slice << 4) + ((m + slice) & 15);
            const float4 x0 = H00[ci], x1 = H01[ci];
            const float4 y0 = H10[ci], y1 = H11[ci];
            a00 = fmaf(w0[m].x, x0.x, a00); a00 = fmaf(w0[m].y, x0.y, a00);
            a00 = fmaf(w0[m].z, x0.z, a00); a00 = fmaf(w0[m].w, x0.w, a00);
            a01 = fmaf(w0[m].x, x1.x, a01); a01 = fmaf(w0[m].y, x1.y, a01);
            a01 = fmaf(w0[m].z, x1.z, a01); a01 = fmaf(w0[m].w, x1.w, a01);
            a10 = fmaf(w1i[m].x, x0.x, a10); a10 = fmaf(w1i[m].y, x0.y, a10);
            a10 = fmaf(w1i[m].z, x0.z, a10); a10 = fmaf(w1i[m].w, x0.w, a10);
            a10 = fmaf(w1h[m].x, y0.x, a10); a10 = fmaf(w1h[m].y, y0.y, a10);
            a10 = fmaf(w1h[m].z, y0.z, a10); a10 = fmaf(w1h[m].w, y0.w, a10);
            a11 = fmaf(w1i[m].x, x1.x, a11); a11 = fmaf(w1i[m].y, x1.y, a11);
            a11 = fmaf(w1i[m].z, x1.z, a11); a11 = fmaf(w1i[m].w, x1.w, a11);
            a11 = fmaf(w1h[m].x, y1.x, a11); a11 = fmaf(w1h[m].y, y1.y, a11);
            a11 = fmaf(w1h[m].z, y1.z, a11); a11 = fmaf(w1h[m].w, y1.w, a11);
        }
        a00 += __shfl_xor(a00, 16); a00 += __shfl_xor(a00, 32);
        a01 += __shfl_xor(a01, 16); a01 += __shfl_xor(a01, 32);
        a10 += __shfl_xor(a10, 16); a10 += __shfl_xor(a10, 32);
        a11 += __shfl_xor(a11, 16); a11 += __shfl_xor(a11, 32);
        const int wv = t >> 6, lane = t & 63;
        if (lane < 16) {
            red[wv][0][lane] = a00; red[wv][1][lane] = a01;
            red[wv][2][lane] = a10; red[wv][3][lane] = a11;
        }
        __syncthreads();

        // ---- tail: wave 0 only ----
        if (t < 64) {
            const int lb = t >> 4, rr = t & 15;
            float s = red[0][lb][rr] + red[1][lb][rr] + red[2][lb][rr] + red[3][lb][rr];
            s += (lb < 2) ? gpre : bl1s[rr];
            // lane lb*16+rr holds gate (rr>>2) of unit (rr&3), layer=lb>>1, br=lb&1
            const int src0 = ((t >> 2) << 4) + (t & 3);   // meaningful for t<16
            const float gi = __shfl(s, src0);
            const float gf = __shfl(s, src0 + 4);
            const float gg = __shfl(s, src0 + 8);
            const float go = __shfl(s, src0 + 12);
            if (t < 16) {
                const int layer = t >> 3, br = (t >> 2) & 1, u = t & 3;
                const bool active = (layer == 0) ? (tick < T_SEQ) : (tick >= 1);
                if (active) {
                    const float c = sigm(gf) * creg + sigm(gi) * tanhf(gg);
                    const float h = sigm(go) * tanhf(c);
                    creg = c;
                    __hip_atomic_store(&hbuf[(tick & 1) * 4096 + layer * 2048 + br * 1024 + b * 4 + u],
                                       h, __ATOMIC_RELAXED, __HIP_MEMORY_SCOPE_AGENT);
                    if (layer == 1 && tick == T_SEQ)
                        o_out[br * 1024 + b * 4 + u] = h;
                }
            }
            if (tick < T_SEQ) {
                asm volatile("s_waitcnt vmcnt(0)" ::: "memory");  // h at LLC
                wave0_barrier(bar, (uint32_t)tick + 2u, t);
            }
        }
        __syncthreads();
    }
}

// ---------------------------------------------------------------------------
// out = 5*exp(-sum |o1 - o2|)
// ---------------------------------------------------------------------------
__global__ void __launch_bounds__(256) dist_kernel(const float* __restrict__ o,
                                                   float* __restrict__ out)
{
    int t = threadIdx.x;
    float s = 0.f;
    for (int i = t; i < 1024; i += 256) s += fabsf(o[i] - o[i + 1024]);
#pragma unroll
    for (int off = 1; off < 64; off <<= 1) s += __shfl_xor(s, off);
    __shared__ float r[4];
    if ((t & 63) == 0) r[t >> 6] = s;
    __syncthreads();
    if (t == 0) out[0] = 5.0f * expf(-(r[0] + r[1] + r[2] + r[3]));
}

// ---------------------------------------------------------------------------
extern "C" void kernel_launch(void* const* d_in, const int* in_sizes, int n_in,
                              void* d_out, int out_size, void* d_ws, size_t ws_size,
                              hipStream_t stream) {
    const float* s1   = (const float*)d_in[0];
    const float* s2   = (const float*)d_in[1];
    const float* h1_0 = (const float*)d_in[2];
    const float* c1_0 = (const float*)d_in[3];
    const float* h2_0 = (const float*)d_in[4];
    const float* c2_0 = (const float*)d_in[5];
    const float* W_ih = (const float*)d_in[6];
    const float* W_hh = (const float*)d_in[7];
    const float* b_ih = (const float*)d_in[8];
    const float* b_hh = (const float*)d_in[9];

    uint8_t* w8 = (uint8_t*)d_ws;
    uint32_t* bar  = (uint32_t*)(w8);            // 8 KB barrier region
    float* hbuf  = (float*)(w8 + 8192);          // 32 KB: [2][2][2][1024]
    float* o_out = (float*)(w8 + 8192 + 32768);  // 8 KB:  [2][1024]
    float* G     = (float*)(w8 + 65536);         // 128 MB: [2][T][4096]

    hipMemsetAsync(d_ws, 0, 8192, stream);       // zero barrier counters

    // Phase 1: layer-0 input GEMM for both branches (permuted output)
    dim3 ggrid(32, 64);
    gemm_nt_bias<<<ggrid, 256, 0, stream>>>(s1, s2, W_ih, b_ih, b_hh, G);

    // Phase 2: fused layer-pipelined recurrence (single cooperative dispatch)
    {
        const float* whh = W_hh; const float* wih = W_ih;
        const float* bi = b_ih;  const float* bh = b_hh;
        const float* gg = G;
        const float* h1p = h1_0; const float* c1p = c1_0;
        const float* h2p = h2_0; const float* c2p = c2_0;
        float* hb = hbuf; float* oo = o_out; uint32_t* br = bar;
        void* args[] = { &whh, &wih, &bi, &bh, &gg,
                         &h1p, &c1p, &h2p, &c2p, &hb, &oo, &br };
        hipLaunchCooperativeKernel(lstm_fused, dim3(256), dim3(256), args, 0, stream);
    }

    // Phase 3: scalar output
    dist_kernel<<<1, 256, 0, stream>>>(o_out, (float*)d_out);
}